// Round 3
// baseline (592.923 us; speedup 1.0000x reference)
//
#include <hip/hip_runtime.h>
#include <hip/hip_bf16.h>

#define N_NODES 100000
#define N_EDGES 600000
#define HID 128
#define OUTD 64

typedef unsigned short u16;
typedef unsigned int u32;
typedef __attribute__((ext_vector_type(8))) short bf16x8;
typedef __attribute__((ext_vector_type(4))) float f32x4;

__device__ __forceinline__ float bf2f(u16 u){
  union { u32 u; float f; } v; v.u = ((u32)u) << 16; return v.f;
}
__device__ __forceinline__ u16 f2bf(float f){
  union { float f; u32 u; } v; v.f = f;
  u32 r = v.u + 0x7fffu + ((v.u >> 16) & 1u);
  return (u16)(r >> 16);
}
__device__ __forceinline__ float sigf(float x){ return 1.f/(1.f + __expf(-x)); }
__device__ __forceinline__ float tanhfast(float x){ return 2.f/(1.f + __expf(-2.f*x)) - 1.f; }

// load 8 consecutive fp32, round to bf16x8 fragment
__device__ __forceinline__ bf16x8 cvt8(const float* p){
  f32x4 a = *(const f32x4*)p;
  f32x4 b = *(const f32x4*)(p + 4);
  bf16x8 r;
  r[0]=(short)f2bf(a[0]); r[1]=(short)f2bf(a[1]); r[2]=(short)f2bf(a[2]); r[3]=(short)f2bf(a[3]);
  r[4]=(short)f2bf(b[0]); r[5]=(short)f2bf(b[1]); r[6]=(short)f2bf(b[2]); r[7]=(short)f2bf(b[3]);
  return r;
}

// ---------------- CSR build ----------------
__global__ void k_hist(const int* __restrict__ dst, int* __restrict__ cnt){
  int e = blockIdx.x*256 + threadIdx.x;
  if (e < N_EDGES) atomicAdd(&cnt[dst[e]], 1);
}

__global__ void k_scan1(const int* __restrict__ cnt, int* __restrict__ part, int* __restrict__ bsum){
  __shared__ int s[256];
  int t = threadIdx.x, i = blockIdx.x*256 + t;
  int v = (i < N_NODES) ? cnt[i] : 0;
  s[t] = v; __syncthreads();
  for (int off = 1; off < 256; off <<= 1){
    int x = (t >= off) ? s[t-off] : 0;
    __syncthreads();
    s[t] += x;
    __syncthreads();
  }
  if (i < N_NODES) part[i] = s[t] - v;
  if (t == 255) bsum[blockIdx.x] = s[255];
}

__global__ void k_scan2(const int* __restrict__ bsum, int* __restrict__ boff, int nb){
  __shared__ int s[512];
  int t = threadIdx.x;
  int v = (t < nb) ? bsum[t] : 0;
  s[t] = v; __syncthreads();
  for (int off = 1; off < 512; off <<= 1){
    int x = (t >= off) ? s[t-off] : 0;
    __syncthreads();
    s[t] += x;
    __syncthreads();
  }
  if (t < nb) boff[t] = s[t] - v;
}

__global__ void k_scan3(const int* __restrict__ part, const int* __restrict__ boff, int* __restrict__ rp){
  int i = blockIdx.x*256 + threadIdx.x;
  if (i < N_NODES) rp[i] = part[i] + boff[i >> 8];
  if (i == 0) rp[N_NODES] = N_EDGES;
}

__global__ void k_fill(const int* __restrict__ src, const int* __restrict__ dst,
                       const int* __restrict__ rp, int* __restrict__ cur, int* __restrict__ eidx){
  int e = blockIdx.x*256 + threadIdx.x;
  if (e >= N_EDGES) return;
  int d = dst[e];
  int p = atomicAdd(&cur[d], 1);
  eidx[rp[d] + p] = src[e];
}

// ---------------- GEMM: C[M,NOUT] = act(A[M,128] @ W[NOUT,128]^T + b) ----------------
// W,b fp32 (converted to bf16 fragments once per wave). A fp32 or bf16 per AFP32.
template<int NOUT, int RELU, int AFP32, int WBF, int WF32>
__global__ __launch_bounds__(256, 2) void k_gemm(
    const void* __restrict__ Av, const float* __restrict__ W, const float* __restrict__ bias,
    u16* __restrict__ Cb, float* __restrict__ Cf)
{
  constexpr int NT = NOUT/16;
  const int lane = threadIdx.x & 63;
  const int wib  = threadIdx.x >> 6;
  const int gw   = blockIdx.x * 4 + wib;
  const int nw   = gridDim.x * 4;
  const int ri   = lane & 15;   // A-row / W-row (=C-col) within tile
  const int kg   = lane >> 4;   // k-group

  bf16x8 wf[NT][4];
  #pragma unroll
  for (int t = 0; t < NT; t++)
    #pragma unroll
    for (int kc = 0; kc < 4; kc++)
      wf[t][kc] = cvt8(W + (size_t)(t*16 + ri)*HID + kc*32 + kg*8);
  float bv[NT];
  #pragma unroll
  for (int t = 0; t < NT; t++) bv[t] = bias[t*16 + ri];

  for (int rc = gw; rc < N_NODES/16; rc += nw) {
    bf16x8 af[4];
    if (AFP32) {
      const float* ap = (const float*)Av + (size_t)(rc*16 + ri)*HID;
      #pragma unroll
      for (int kc = 0; kc < 4; kc++) af[kc] = cvt8(ap + kc*32 + kg*8);
    } else {
      const u16* ap = (const u16*)Av + (size_t)(rc*16 + ri)*HID;
      #pragma unroll
      for (int kc = 0; kc < 4; kc++) af[kc] = *(const bf16x8*)(ap + kc*32 + kg*8);
    }

    f32x4 acc[NT];
    #pragma unroll
    for (int t = 0; t < NT; t++) acc[t] = (f32x4){0.f,0.f,0.f,0.f};
    #pragma unroll
    for (int kc = 0; kc < 4; kc++)
      #pragma unroll
      for (int t = 0; t < NT; t++)
        acc[t] = __builtin_amdgcn_mfma_f32_16x16x32_bf16(af[kc], wf[t][kc], acc[t], 0, 0, 0);

    #pragma unroll
    for (int t = 0; t < NT; t++)
      #pragma unroll
      for (int j = 0; j < 4; j++){
        float v = acc[t][j] + bv[t];
        if (RELU) v = fmaxf(v, 0.f);
        int row = rc*16 + kg*4 + j;
        int col = t*16 + ri;
        if (WBF) Cb[(size_t)row*NOUT + col] = f2bf(v);
        if (WF32) Cf[(size_t)row*NOUT + col] = v;
      }
  }
}

// ---------------- edge aggregation: a[n][:] = sum over incoming edges of wh[src][:] ----------------
// one wave per node; lane covers 2 features via u32 load (256B contiguous per edge row)
__global__ void k_gather(const u16* __restrict__ wh, const int* __restrict__ rp,
                         const int* __restrict__ eidx, u16* __restrict__ a){
  int w   = (blockIdx.x * 256 + threadIdx.x) >> 6;
  int nwv = (gridDim.x * 256) >> 6;
  int lane = threadIdx.x & 63;
  for (int n = w; n < N_NODES; n += nwv){
    int s = rp[n], e = rp[n+1];
    float a0 = 0.f, a1 = 0.f;
    for (int i = s; i < e; ++i){
      int sn = eidx[i];
      u32 v = *(const u32*)(wh + (size_t)sn*HID + lane*2);
      a0 += bf2f((u16)(v & 0xffffu));
      a1 += bf2f((u16)(v >> 16));
    }
    u32 o = ((u32)f2bf(a1) << 16) | (u32)f2bf(a0);
    *(u32*)(a + (size_t)n*HID + lane*2) = o;
  }
}

// ---------------- fused GRU ----------------
// wave owns gate-col tile ct (16 cols); hF (fp32 master) updated in place, unique ownership;
// bf16 h ping-pongs (other waves read full rows of hBin).
__global__ __launch_bounds__(256, 2) void k_gru(
    const u16* __restrict__ aB, const u16* __restrict__ hBin,
    const float* __restrict__ Wih, const float* __restrict__ Whh,
    const float* __restrict__ bih, const float* __restrict__ bhh,
    float* __restrict__ hF, u16* __restrict__ hBout)
{
  const int lane = threadIdx.x & 63;
  const int wib  = threadIdx.x >> 6;
  const int gw   = blockIdx.x * 4 + wib;
  const int nw   = gridDim.x * 4;   // multiple of 8 -> ct invariant across grid-stride
  const int ri   = lane & 15;
  const int kg   = lane >> 4;
  const int ct   = gw & 7;

  bf16x8 wf[6][4];
  #pragma unroll
  for (int g = 0; g < 3; g++)
    #pragma unroll
    for (int kc = 0; kc < 4; kc++){
      wf[g][kc]   = cvt8(Wih + (size_t)(g*HID + ct*16 + ri)*HID + kc*32 + kg*8);
      wf[3+g][kc] = cvt8(Whh + (size_t)(g*HID + ct*16 + ri)*HID + kc*32 + kg*8);
    }
  float bir = bih[ct*16+ri], biz = bih[HID+ct*16+ri], bin_ = bih[2*HID+ct*16+ri];
  float bhr = bhh[ct*16+ri], bhz = bhh[HID+ct*16+ri], bhn  = bhh[2*HID+ct*16+ri];

  const int U = (N_NODES/16) * 8;
  for (int u = gw; u < U; u += nw) {
    int rc = u >> 3;
    const u16* ap = aB   + (size_t)(rc*16 + ri)*HID;
    const u16* hp = hBin + (size_t)(rc*16 + ri)*HID;
    bf16x8 af[4], hf[4];
    #pragma unroll
    for (int kc = 0; kc < 4; kc++){
      af[kc] = *(const bf16x8*)(ap + kc*32 + kg*8);
      hf[kc] = *(const bf16x8*)(hp + kc*32 + kg*8);
    }
    f32x4 acc[6];
    #pragma unroll
    for (int t = 0; t < 6; t++) acc[t] = (f32x4){0.f,0.f,0.f,0.f};
    #pragma unroll
    for (int kc = 0; kc < 4; kc++)
      #pragma unroll
      for (int g = 0; g < 3; g++){
        acc[g]   = __builtin_amdgcn_mfma_f32_16x16x32_bf16(af[kc], wf[g][kc],   acc[g],   0, 0, 0);
        acc[3+g] = __builtin_amdgcn_mfma_f32_16x16x32_bf16(hf[kc], wf[3+g][kc], acc[3+g], 0, 0, 0);
      }
    #pragma unroll
    for (int j = 0; j < 4; j++){
      float r  = sigf(acc[0][j] + bir + acc[3][j] + bhr);
      float z  = sigf(acc[1][j] + biz + acc[4][j] + bhz);
      float nn = tanhfast(acc[2][j] + bin_ + r*(acc[5][j] + bhn));
      int row = rc*16 + kg*4 + j;
      int col = ct*16 + ri;
      size_t idx = (size_t)row*HID + col;
      float ho = hF[idx];
      float hn = (1.f - z)*nn + z*ho;
      hF[idx] = hn;
      hBout[idx] = f2bf(hn);
    }
  }
}

extern "C" void kernel_launch(void* const* d_in, const int* in_sizes, int n_in,
                              void* d_out, int out_size, void* d_ws, size_t ws_size,
                              hipStream_t stream)
{
  const float* x    = (const float*)d_in[0];
  const int*   src  = (const int*)d_in[1];
  const int*   dst  = (const int*)d_in[2];
  const float* Win  = (const float*)d_in[3];
  const float* bin  = (const float*)d_in[4];
  const float* We   = (const float*)d_in[5];
  const float* be   = (const float*)d_in[6];
  const float* Wih  = (const float*)d_in[7];
  const float* bih  = (const float*)d_in[8];
  const float* Whh  = (const float*)d_in[9];
  const float* bhh  = (const float*)d_in[10];
  const float* Wout = (const float*)d_in[11];
  const float* bout = (const float*)d_in[12];
  float* out = (float*)d_out;

  char* w = (char*)d_ws;
  auto alloc = [&](size_t bytes)->char*{ char* p = w; w += (bytes + 255) & ~(size_t)255; return p; };
  float* hF  = (float*) alloc((size_t)N_NODES*HID*4);   // fp32 master h
  u16*   hB0 = (u16*)   alloc((size_t)N_NODES*HID*2);
  u16*   hB1 = (u16*)   alloc((size_t)N_NODES*HID*2);
  u16*   whB = (u16*)   alloc((size_t)N_NODES*HID*2);
  u16*   aB  = (u16*)   alloc((size_t)N_NODES*HID*2);
  int* cnt  = (int*)alloc((size_t)N_NODES*4);
  int* rp   = (int*)alloc((size_t)(N_NODES+1)*4);
  int* part = (int*)alloc((size_t)N_NODES*4);
  int* bsum = (int*)alloc(512*4);
  int* boff = (int*)alloc(512*4);
  int* cur  = (int*)alloc((size_t)N_NODES*4);
  int* eidx = (int*)alloc((size_t)N_EDGES*4);

  (void)hipMemsetAsync(cnt, 0, (size_t)N_NODES*4, stream);
  (void)hipMemsetAsync(cur, 0, (size_t)N_NODES*4, stream);

  const int eb = (N_EDGES + 255)/256;   // 2344
  const int nb = (N_NODES + 255)/256;   // 391
  k_hist <<<eb, 256, 0, stream>>>(dst, cnt);
  k_scan1<<<nb, 256, 0, stream>>>(cnt, part, bsum);
  k_scan2<<<1, 512, 0, stream>>>(bsum, boff, nb);
  k_scan3<<<nb, 256, 0, stream>>>(part, boff, rp);
  k_fill <<<eb, 256, 0, stream>>>(src, dst, rp, cur, eidx);

  // h0 = relu(x @ Win^T + bin) -> hF (f32) + hB0 (bf16)
  k_gemm<HID, 1, 1, 1, 1><<<512, 256, 0, stream>>>((const void*)x, Win, bin, hB0, hF);

  u16* hcur = hB0; u16* hnxt = hB1;
  for (int s = 0; s < 3; s++){
    // wh = hcur @ We^T + be  (bf16 out)
    k_gemm<HID, 0, 0, 1, 0><<<512, 256, 0, stream>>>((const void*)hcur, We, be, whB, nullptr);
    // a = segment_sum(wh[src], dst)  (fp32 reg accumulate, bf16 store)
    k_gather<<<2048, 256, 0, stream>>>(whB, rp, eidx, aB);
    // GRU: h = (1-z)*n + z*h
    k_gru<<<512, 256, 0, stream>>>(aB, hcur, Wih, Whh, bih, bhh, hF, hnxt);
    u16* t = hcur; hcur = hnxt; hnxt = t;
  }

  // out = h @ Wout^T + bout  (fp32 out)
  k_gemm<OUTD, 0, 0, 0, 1><<<512, 256, 0, stream>>>((const void*)hcur, Wout, bout, nullptr, out);
}